// Round 14
// baseline (69.802 us; speedup 1.0000x reference)
//
#include <hip/hip_runtime.h>
#include <math.h>

#define NR 4096
#define HD 512
#define NJR 32
#define INV_T 10.0f
#define DONE_FINAL 1024

typedef __attribute__((ext_vector_type(8))) short bf16x8;
typedef __attribute__((ext_vector_type(4))) short short4v;
typedef __attribute__((ext_vector_type(4))) float f32x4;

typedef const unsigned int __attribute__((address_space(1)))* gas_t;
typedef unsigned int __attribute__((address_space(3)))* las_t;

__device__ __forceinline__ unsigned short f2bf(float f) {
  union { float f; unsigned u; } v; v.f = f;
  unsigned r = v.u + 0x7fff + ((v.u >> 16) & 1);
  return (unsigned short)(r >> 16);
}
__device__ __forceinline__ float bf2f(unsigned short b) {
  union { unsigned u; float f; } v; v.u = ((unsigned)b) << 16;
  return v.f;
}

// ======== fragment-major layout ========
// matrix [M][K]: fragment (rf=r>>4, ks=c>>5) = 1024B slot at (rf*(K>>5)+ks)*1024.
// lane l holds bf16x8 at lane*16: row = rf*16+(l&15), cols ks*32+(l>>4)*4+{0..3,16..19}.

// ---------------------------------------------------------------- prep (R7 verbatim + done zero)
__global__ __launch_bounds__(256) void prep(
    const float* __restrict__ s, const float* __restrict__ sp,
    const float* __restrict__ a1h,
    unsigned short* __restrict__ Sb, unsigned short* __restrict__ SPb,
    int* __restrict__ aidx,
    const float* __restrict__ pW0, unsigned short* __restrict__ pW0t,
    const float* __restrict__ pW1, unsigned short* __restrict__ pW1t,
    const float* __restrict__ pW2, unsigned short* __restrict__ pW2t,
    const float* __restrict__ gW0, unsigned short* __restrict__ gW0t,
    const float* __restrict__ gW1, unsigned short* __restrict__ gW1t,
    const float* __restrict__ gW2, unsigned short* __restrict__ gW2t,
    unsigned* __restrict__ done, float* __restrict__ out) {
  int b = blockIdx.x, tid = threadIdx.x;
  if (b < 16) {
    int r = b * 256 + tid;
    int a = 0;
#pragma unroll
    for (int j = 0; j < 4; ++j) if (a1h[(size_t)r * 4 + j] > 0.5f) a = j;
    aidx[r] = a;
    if (b == 0 && tid == 0) out[0] = 0.f;
    if (b == 1) { for (int i = tid; i < 1025; i += 256) done[i] = 0; }
    return;
  }
  const int idx8 = tid & 127;
  const int h = idx8 & 1, p = idx8 >> 1, hi = p >> 4, l15 = p & 15;
  if (b < 2064) {
    const float* src = (b < 1040) ? s : sp;
    unsigned short* dst = (b < 1040) ? Sb : SPb;
    int lb = (b < 1040) ? b - 16 : b - 1040;
    int s0 = lb * 2 + (tid >> 7);
    int rf = s0 >> 3, ks = s0 & 7;
    int row = rf * 16 + l15, c0 = ks * 32 + hi * 4 + h * 16;
    float4 v = *(const float4*)&src[(size_t)row * 256 + c0];
    short4v o = { (short)f2bf(v.x), (short)f2bf(v.y), (short)f2bf(v.z), (short)f2bf(v.w) };
    *(short4v*)((char*)dst + (size_t)s0 * 1024 + idx8 * 8) = o;
    return;
  }
  int local = b - 2064;
  const float* W; unsigned short* Wt; int N, ksh;
  if (local < 128)      { W = pW0; Wt = pW0t; N = 512; ksh = 3; }
  else if (local < 384) { W = pW1; Wt = pW1t; N = 512; ksh = 4; local -= 128; }
  else if (local < 448) { W = pW2; Wt = pW2t; N = 128; ksh = 4; local -= 384; }
  else if (local < 576) { W = gW0; Wt = gW0t; N = 512; ksh = 3; local -= 448; }
  else if (local < 832) { W = gW1; Wt = gW1t; N = 512; ksh = 4; local -= 576; }
  else                  { W = gW2; Wt = gW2t; N = 128; ksh = 4; local -= 832; }
  int s0 = local * 2 + (tid >> 7);
  int rf = s0 >> ksh, ks = s0 & ((1 << ksh) - 1);
  int n = rf * 16 + l15, k0 = ks * 32 + hi * 4 + h * 16;
  short4v o = { (short)f2bf(W[(size_t)(k0 + 0) * N + n]),
                (short)f2bf(W[(size_t)(k0 + 1) * N + n]),
                (short)f2bf(W[(size_t)(k0 + 2) * N + n]),
                (short)f2bf(W[(size_t)(k0 + 3) * N + n]) };
  *(short4v*)((char*)Wt + (size_t)s0 * 1024 + idx8 * 8) = o;
}

// ---------------------------------------------------------------- triple-buffered GEMM (R7 verbatim)
template <int BM, int K, bool RELU, bool GB, bool SQ>
__global__ __launch_bounds__(256) void gemm_p3(
    const unsigned short* __restrict__ A0, const unsigned short* __restrict__ A1,
    const unsigned short* __restrict__ W0, const unsigned short* __restrict__ W1,
    const float* __restrict__ b0, const float* __restrict__ b1,
    unsigned short* __restrict__ C0, unsigned short* __restrict__ C1,
    float* __restrict__ sqp2, int N,
    const int* __restrict__ aidx, const float* __restrict__ gW0f) {
  constexpr int KS = K >> 5;
  constexpr int NSTEP = K >> 6;
  constexpr int ABYTES = BM * 128;
  constexpr int BBYTES = 8192;
  constexpr int NA = BM >> 5;
  constexpr int WM_FR = BM >> 5;
  constexpr int V = NA + 2;
  __shared__ char lds[3 * (ABYTES + BBYTES)];
  char* AsB = lds;
  char* BsB = lds + 3 * ABYTES;

  const int tid = threadIdx.x, lane = tid & 63, w = tid >> 6;
  const int wm = w >> 1, wn = w & 1;
  const int z = blockIdx.z;
  const char* Ab = (const char*)(z ? A1 : A0);
  const char* Wb = (const char*)(z ? W1 : W0);
  const float* bias = z ? b1 : b0;
  char* Cb = (char*)(z ? C1 : C0);
  const int bm = blockIdx.x * BM, bn = blockIdx.y * 64;
  const int lane16 = lane * 16;

  auto stage = [&](int buf, int st) {
#pragma unroll
    for (int u = 0; u < NA; ++u) {
      const int sl = w * NA + u;
      const char* src = Ab + ((size_t)((bm >> 4) + (sl >> 1)) * KS + st * 2 + (sl & 1)) * 1024 + lane16;
      __builtin_amdgcn_global_load_lds((gas_t)src, (las_t)(AsB + buf * ABYTES + sl * 1024), 16, 0, 0);
    }
#pragma unroll
    for (int u = 0; u < 2; ++u) {
      const int sl = w * 2 + u;
      const char* src = Wb + ((size_t)((bn >> 4) + (sl >> 1)) * KS + st * 2 + (sl & 1)) * 1024 + lane16;
      __builtin_amdgcn_global_load_lds((gas_t)src, (las_t)(BsB + buf * BBYTES + sl * 1024), 16, 0, 0);
    }
  };

  f32x4 acc[WM_FR][2] = {};
  stage(0, 0);
  stage(1, 1);
#pragma unroll
  for (int st = 0; st < NSTEP; ++st) {
    const int buf = st % 3;
    if (st + 2 < NSTEP) {
      stage((st + 2) % 3, st + 2);
      if constexpr (V == 6) asm volatile("s_waitcnt vmcnt(12)" ::: "memory");
      else                  asm volatile("s_waitcnt vmcnt(8)" ::: "memory");
    } else if (st + 1 < NSTEP) {
      if constexpr (V == 6) asm volatile("s_waitcnt vmcnt(6)" ::: "memory");
      else                  asm volatile("s_waitcnt vmcnt(4)" ::: "memory");
    } else {
      asm volatile("s_waitcnt vmcnt(0)" ::: "memory");
    }
    __builtin_amdgcn_s_barrier();
#pragma unroll
    for (int kss = 0; kss < 2; ++kss) {
      bf16x8 af[WM_FR], bfv[2];
#pragma unroll
      for (int i = 0; i < WM_FR; ++i)
        af[i] = *(const bf16x8*)(AsB + buf * ABYTES + ((wm * WM_FR + i) * 2 + kss) * 1024 + lane16);
#pragma unroll
      for (int j = 0; j < 2; ++j)
        bfv[j] = *(const bf16x8*)(BsB + buf * BBYTES + ((wn * 2 + j) * 2 + kss) * 1024 + lane16);
#pragma unroll
      for (int i = 0; i < WM_FR; ++i)
#pragma unroll
        for (int j = 0; j < 2; ++j)
          acc[i][j] = __builtin_amdgcn_mfma_f32_16x16x32_bf16(bfv[j], af[i], acc[i][j], 0, 0, 0);
    }
    __builtin_amdgcn_s_barrier();
  }

  const int l15 = lane & 15, hi = lane >> 4;
  const int NS = N >> 5;
  const int row0 = bm + wm * (BM / 2);
  const int col0 = bn + wn * 32;
  float sq[WM_FR];
  int ar[WM_FR];
#pragma unroll
  for (int i = 0; i < WM_FR; ++i) { sq[i] = 0.f; ar[i] = 0; }
  if (GB && z == 1) {
#pragma unroll
    for (int i = 0; i < WM_FR; ++i) ar[i] = aidx[row0 + i * 16 + l15];
  }
  float4 bi0 = *(const float4*)&bias[col0 + hi * 4];
  float4 bi1 = *(const float4*)&bias[col0 + 16 + hi * 4];
#pragma unroll
  for (int i = 0; i < WM_FR; ++i) {
    const int rfC = (row0 >> 4) + i;
    float v[8] = { acc[i][0][0] + bi0.x, acc[i][0][1] + bi0.y,
                   acc[i][0][2] + bi0.z, acc[i][0][3] + bi0.w,
                   acc[i][1][0] + bi1.x, acc[i][1][1] + bi1.y,
                   acc[i][1][2] + bi1.z, acc[i][1][3] + bi1.w };
    if (GB && z == 1) {
      float4 g0 = *(const float4*)&gW0f[(size_t)(256 + ar[i]) * N + col0 + hi * 4];
      float4 g1 = *(const float4*)&gW0f[(size_t)(256 + ar[i]) * N + col0 + 16 + hi * 4];
      v[0] += g0.x; v[1] += g0.y; v[2] += g0.z; v[3] += g0.w;
      v[4] += g1.x; v[5] += g1.y; v[6] += g1.z; v[7] += g1.w;
    }
    bf16x8 r;
#pragma unroll
    for (int t = 0; t < 8; ++t) {
      float vv = RELU ? fmaxf(v[t], 0.f) : v[t];
      unsigned short cv = f2bf(vv);
      r[t] = (short)cv;
      if (SQ) { float vb = bf2f(cv); sq[i] += vb * vb; }
    }
    *(bf16x8*)(Cb + (size_t)(rfC * NS + (col0 >> 5)) * 1024 + lane16) = r;
  }
  if (SQ && z == 1) {
#pragma unroll
    for (int i = 0; i < WM_FR; ++i) {
      float t = sq[i];
      t += __shfl_xor(t, 16, 64);
      t += __shfl_xor(t, 32, 64);
      if (lane < 16) sqp2[(size_t)(col0 >> 5) * NR + row0 + i * 16 + lane] = t;
    }
  }
}

// ---------------------------------------------------------------- logits + tail finalize
// grid (32, 32): block = 128 rows x 128 j; Zp panel LDS-staged; last-16 blocks finalize.
__global__ __launch_bounds__(256) void logits_fin(
    const unsigned short* __restrict__ Zb, const unsigned short* __restrict__ Zpb,
    const float* __restrict__ sqp4, float* __restrict__ wm_,
    float* __restrict__ wsum, float* __restrict__ wdiag,
    unsigned* __restrict__ done, float* __restrict__ out) {
  __shared__ __align__(1024) char Ps[32768];
  __shared__ int hid;
  __shared__ float fpart[4];
  const int tid = threadIdx.x, lane = tid & 63, w = tid >> 6;
  const int l15 = lane & 15, hi = lane >> 4;
  const int bx = blockIdx.x, jr = blockIdx.y;
  const int i0 = bx * 128;
  const int row32 = i0 + w * 32;
  const int jbase = jr * 128;
  const int lane16 = lane * 16;
  const char* Zc = (const char*)Zb;
  const char* Pc = (const char*)Zpb;

  // stage the 32KB contiguous Zp j-panel into LDS (shared by 4 waves)
#pragma unroll
  for (int u = 0; u < 8; ++u) {
    const int sl = w * 8 + u;
    __builtin_amdgcn_global_load_lds(
        (gas_t)(Pc + ((size_t)(jbase >> 4) * 4 + sl) * 1024 + lane16),
        (las_t)(Ps + sl * 1024), 16, 0, 0);
  }
  bf16x8 afr[2][4];
#pragma unroll
  for (int rf = 0; rf < 2; ++rf)
#pragma unroll
    for (int ks = 0; ks < 4; ++ks)
      afr[rf][ks] = *(const bf16x8*)(Zc + (size_t)(((row32 >> 4) + rf) * 4 + ks) * 1024 + lane16);
  // hoisted ||zp_j||^2 (4 partial arrays summed once, reused for both rf)
  f32x4 spq[8];
#pragma unroll
  for (int jf = 0; jf < 8; ++jf) {
    const int cb = jbase + jf * 16 + hi * 4;
    float4 q0 = *(const float4*)&sqp4[cb];
    float4 q1 = *(const float4*)&sqp4[NR + cb];
    float4 q2 = *(const float4*)&sqp4[2 * NR + cb];
    float4 q3 = *(const float4*)&sqp4[3 * NR + cb];
    spq[jf][0] = q0.x + q1.x + q2.x + q3.x;
    spq[jf][1] = q0.y + q1.y + q2.y + q3.y;
    spq[jf][2] = q0.z + q1.z + q2.z + q3.z;
    spq[jf][3] = q0.w + q1.w + q2.w + q3.w;
  }
  asm volatile("s_waitcnt vmcnt(0)" ::: "memory");
  __syncthreads();

  f32x4 acc[2][8] = {};
#pragma unroll
  for (int ks = 0; ks < 4; ++ks)
#pragma unroll
    for (int jf = 0; jf < 8; ++jf) {
      bf16x8 bfv = *(const bf16x8*)(Ps + (jf * 4 + ks) * 1024 + lane16);
      acc[0][jf] = __builtin_amdgcn_mfma_f32_16x16x32_bf16(bfv, afr[0][ks], acc[0][jf], 0, 0, 0);
      acc[1][jf] = __builtin_amdgcn_mfma_f32_16x16x32_bf16(bfv, afr[1][ks], acc[1][jf], 0, 0, 0);
    }

#pragma unroll
  for (int rf = 0; rf < 2; ++rf) {
    const int grow = row32 + rf * 16 + l15;
    float mx = -INFINITY, dd = 0.f;
    bool hasd = false;
#pragma unroll
    for (int jf = 0; jf < 8; ++jf) {
      const int cb = jbase + jf * 16 + hi * 4;
#pragma unroll
      for (int e = 0; e < 4; ++e) {
        float lv = (2.f * acc[rf][jf][e] - spq[jf][e]) * INV_T;
        acc[rf][jf][e] = lv;
        mx = fmaxf(mx, lv);
        if (cb + e == grow) { dd = lv; hasd = true; }
      }
    }
    mx = fmaxf(mx, __shfl_xor(mx, 16, 64));
    mx = fmaxf(mx, __shfl_xor(mx, 32, 64));
    float sum = 0.f;
#pragma unroll
    for (int jf = 0; jf < 8; ++jf)
#pragma unroll
      for (int e = 0; e < 4; ++e) sum += __expf(acc[rf][jf][e] - mx);
    sum += __shfl_xor(sum, 16, 64);
    sum += __shfl_xor(sum, 32, 64);
    if (hi == 0) {
      wm_[(size_t)jr * NR + grow] = mx;
      wsum[(size_t)jr * NR + grow] = sum;
    }
    if (hasd) wdiag[grow] = dd;
  }

  // ---- arrival protocol: 64 spread lines (16 blocks each), then final counter ----
  __syncthreads();
  if (tid == 0) {
    hid = -1;
    const int bid = jr * 32 + bx;
    unsigned old = __hip_atomic_fetch_add(&done[(bid & 63) * 16], 1u,
                                          __ATOMIC_ACQ_REL, __HIP_MEMORY_SCOPE_AGENT);
    if (old == 15u) {
      unsigned f = __hip_atomic_fetch_add(&done[DONE_FINAL], 1u,
                                          __ATOMIC_ACQ_REL, __HIP_MEMORY_SCOPE_AGENT);
      if (f >= 48u) {
        while (__hip_atomic_load(&done[DONE_FINAL], __ATOMIC_ACQUIRE,
                                 __HIP_MEMORY_SCOPE_AGENT) < 64u)
          __builtin_amdgcn_s_sleep(16);
        hid = (int)(f - 48u);
      }
    }
  }
  __syncthreads();
  if (hid < 0) return;

  // ---- tail finalize: this block handles rows [hid*256, hid*256+256) ----
  {
    const int r = hid * 256 + tid;
    float mm = wm_[r];
    float ss = wsum[r];
#pragma unroll
    for (int p = 1; p < NJR; ++p) {
      float mo = wm_[(size_t)p * NR + r];
      float so = wsum[(size_t)p * NR + r];
      float mn = fmaxf(mm, mo);
      ss = ss * __expf(mm - mn) + so * __expf(mo - mn);
      mm = mn;
    }
    float v = mm + logf(ss) - wdiag[r];
#pragma unroll
    for (int off = 32; off; off >>= 1) v += __shfl_xor(v, off, 64);
    if (lane == 0) fpart[w] = v;
    __syncthreads();
    if (tid == 0)
      atomicAdd(out, (fpart[0] + fpart[1] + fpart[2] + fpart[3]) * (1.0f / (float)NR));
  }
}

// ---------------------------------------------------------------- launch (5 dispatches)
extern "C" void kernel_launch(void* const* d_in, const int* in_sizes, int n_in,
                              void* d_out, int out_size, void* d_ws, size_t ws_size,
                              hipStream_t stream) {
  const float* s   = (const float*)d_in[0];
  const float* sp  = (const float*)d_in[1];
  const float* a1h = (const float*)d_in[2];
  const float* pW0 = (const float*)d_in[3];
  const float* pb0 = (const float*)d_in[4];
  const float* pW1 = (const float*)d_in[5];
  const float* pb1 = (const float*)d_in[6];
  const float* pW2 = (const float*)d_in[7];
  const float* pb2 = (const float*)d_in[8];
  const float* gW0 = (const float*)d_in[9];
  const float* gb0 = (const float*)d_in[10];
  const float* gW1 = (const float*)d_in[11];
  const float* gb1 = (const float*)d_in[12];
  const float* gW2 = (const float*)d_in[13];
  const float* gb2 = (const float*)d_in[14];

  char* p = (char*)d_ws;
  unsigned short* Sb   = (unsigned short*)p; p += (size_t)NR * 256 * 2;
  unsigned short* SPb  = (unsigned short*)p; p += (size_t)NR * 256 * 2;
  unsigned short* H1   = (unsigned short*)p; p += (size_t)2 * NR * HD * 2;
  unsigned short* H2   = (unsigned short*)p; p += (size_t)2 * NR * HD * 2;
  unsigned short* Zall = (unsigned short*)p; p += (size_t)2 * NR * 128 * 2;
  unsigned short* pW0t = (unsigned short*)p; p += (size_t)256 * 512 * 2;
  unsigned short* pW1t = (unsigned short*)p; p += (size_t)512 * 512 * 2;
  unsigned short* pW2t = (unsigned short*)p; p += (size_t)512 * 128 * 2;
  unsigned short* gW0t = (unsigned short*)p; p += (size_t)256 * 512 * 2;
  unsigned short* gW1t = (unsigned short*)p; p += (size_t)512 * 512 * 2;
  unsigned short* gW2t = (unsigned short*)p; p += (size_t)512 * 128 * 2;
  float* sqp4 = (float*)p; p += (size_t)4 * NR * 4;
  float* wm   = (float*)p; p += (size_t)NJR * NR * 4;
  float* wsm  = (float*)p; p += (size_t)NJR * NR * 4;
  float* wdg  = (float*)p; p += (size_t)NR * 4;
  int*   aidx = (int*)p;  p += (size_t)NR * 4;
  unsigned* done = (unsigned*)p; p += 8192;

  unsigned short* H1g = H1 + (size_t)NR * HD;
  unsigned short* H2g = H2 + (size_t)NR * HD;
  unsigned short* Zb  = Zall;
  unsigned short* Zpb = Zall + (size_t)NR * 128;

  dim3 blk(256);
  prep<<<2960, blk, 0, stream>>>(s, sp, a1h, Sb, SPb, aidx,
                                 pW0, pW0t, pW1, pW1t, pW2, pW2t,
                                 gW0, gW0t, gW1, gW1t, gW2, gW2t,
                                 done, (float*)d_out);

  gemm_p3<128, 256, true, true, false><<<dim3(32, 8, 2), blk, 0, stream>>>(
      Sb, SPb, pW0t, gW0t, pb0, gb0, H1, H1g, nullptr, 512, aidx, gW0);
  gemm_p3<128, 512, true, false, false><<<dim3(32, 8, 2), blk, 0, stream>>>(
      H1, H1g, pW1t, gW1t, pb1, gb1, H2, H2g, nullptr, 512, nullptr, nullptr);
  gemm_p3<64, 512, false, false, true><<<dim3(64, 2, 2), blk, 0, stream>>>(
      H2, H2g, pW2t, gW2t, pb2, gb2, Zb, Zpb, sqp4, 128, nullptr, nullptr);

  logits_fin<<<dim3(32, 32), blk, 0, stream>>>(Zb, Zpb, sqp4, wm, wsm, wdg,
                                               done, (float*)d_out);
}

// Round 15
// 46.008 us; speedup vs baseline: 1.5172x; 1.5172x over previous
//
#include <hip/hip_runtime.h>
#include <math.h>

#define NR 4096
#define HD 512
#define NJR 16
#define INV_T 10.0f

typedef __attribute__((ext_vector_type(8))) short bf16x8;
typedef __attribute__((ext_vector_type(4))) short short4v;
typedef __attribute__((ext_vector_type(4))) float f32x4;

typedef const unsigned int __attribute__((address_space(1)))* gas_t;
typedef unsigned int __attribute__((address_space(3)))* las_t;

__device__ __forceinline__ unsigned short f2bf(float f) {
  union { float f; unsigned u; } v; v.f = f;
  unsigned r = v.u + 0x7fff + ((v.u >> 16) & 1);
  return (unsigned short)(r >> 16);
}
__device__ __forceinline__ float bf2f(unsigned short b) {
  union { unsigned u; float f; } v; v.u = ((unsigned)b) << 16;
  return v.f;
}

// ======== fragment-major layout ========
// matrix [M][K]: fragment (rf=r>>4, ks=c>>5) = 1024B slot at (rf*(K>>5)+ks)*1024.
// lane l holds bf16x8 at lane*16: row = rf*16+(l&15), cols ks*32+(l>>4)*4+{0..3,16..19}.

// ---------------------------------------------------------------- weight transpose-cast unit
__device__ __forceinline__ void wt_unit(int local, int tid, const float* W,
                                        unsigned short* Wt, int N, int ksh) {
  const int idx8 = tid & 127;
  const int h = idx8 & 1, p = idx8 >> 1, hi = p >> 4, l15 = p & 15;
  int s0 = local * 2 + (tid >> 7);
  int rf = s0 >> ksh, ks = s0 & ((1 << ksh) - 1);
  int n = rf * 16 + l15, k0 = ks * 32 + hi * 4 + h * 16;
  short4v o = { (short)f2bf(W[(size_t)(k0 + 0) * N + n]),
                (short)f2bf(W[(size_t)(k0 + 1) * N + n]),
                (short)f2bf(W[(size_t)(k0 + 2) * N + n]),
                (short)f2bf(W[(size_t)(k0 + 3) * N + n]) };
  *(short4v*)((char*)Wt + (size_t)s0 * 1024 + idx8 * 8) = o;
}

// ---------------------------------------------------------------- prep: grid-strided casts + W0 transposes
// units: [0,16) aidx+sqp0+out0 ; [16,2064) casts ; [2064,2192) pW0t ; [2192,2320) gW0t
__global__ __launch_bounds__(256) void prep(
    const float* __restrict__ s, const float* __restrict__ sp,
    const float* __restrict__ a1h,
    unsigned short* __restrict__ Sb, unsigned short* __restrict__ SPb,
    int* __restrict__ aidx, float* __restrict__ sqp,
    const float* __restrict__ pW0, unsigned short* __restrict__ pW0t,
    const float* __restrict__ gW0, unsigned short* __restrict__ gW0t,
    float* __restrict__ out) {
  const int tid = threadIdx.x;
  for (int u = blockIdx.x; u < 2320; u += 580) {
    if (u < 16) {
      int r = u * 256 + tid;
      int a = 0;
#pragma unroll
      for (int j = 0; j < 4; ++j) if (a1h[(size_t)r * 4 + j] > 0.5f) a = j;
      aidx[r] = a;
      sqp[r] = 0.f;
      if (u == 0 && tid == 0) out[0] = 0.f;
      continue;
    }
    if (u < 2064) {
      const int b = u;
      const float* src = (b < 1040) ? s : sp;
      unsigned short* dst = (b < 1040) ? Sb : SPb;
      int lb = (b < 1040) ? b - 16 : b - 1040;
      const int idx8 = tid & 127;
      const int h = idx8 & 1, p = idx8 >> 1, hi = p >> 4, l15 = p & 15;
      int s0 = lb * 2 + (tid >> 7);
      int rf = s0 >> 3, ks = s0 & 7;
      int row = rf * 16 + l15, c0 = ks * 32 + hi * 4 + h * 16;
      float4 v = *(const float4*)&src[(size_t)row * 256 + c0];
      short4v o = { (short)f2bf(v.x), (short)f2bf(v.y), (short)f2bf(v.z), (short)f2bf(v.w) };
      *(short4v*)((char*)dst + (size_t)s0 * 1024 + idx8 * 8) = o;
      continue;
    }
    int local = u - 2064;
    if (local < 128) wt_unit(local, tid, pW0, pW0t, 512, 3);
    else             wt_unit(local - 128, tid, gW0, gW0t, 512, 3);
  }
}

// ---------------------------------------------------------------- triple-buffered GEMM (R7 verbatim body)
// GRID1D: if >=0, 1D launch; bid<GRID1D*? handled by caller mapping. Rider units appended for L0.
template <int BM, int K, bool RELU, bool GB, bool SQ, bool RIDERS>
__global__ __launch_bounds__(256) void gemm_p3(
    const unsigned short* __restrict__ A0, const unsigned short* __restrict__ A1,
    const unsigned short* __restrict__ W0, const unsigned short* __restrict__ W1,
    const float* __restrict__ b0, const float* __restrict__ b1,
    unsigned short* __restrict__ C0, unsigned short* __restrict__ C1,
    float* __restrict__ sqp, int N, int gx, int gy,
    const int* __restrict__ aidx, const float* __restrict__ gW0f,
    const float* __restrict__ rpW1, unsigned short* __restrict__ rpW1t,
    const float* __restrict__ rpW2, unsigned short* __restrict__ rpW2t,
    const float* __restrict__ rgW1, unsigned short* __restrict__ rgW1t,
    const float* __restrict__ rgW2, unsigned short* __restrict__ rgW2t) {
  const int tid = threadIdx.x;
  const int ngemm = gx * gy * 2;
  if (RIDERS && (int)blockIdx.x >= ngemm) {
    int local = blockIdx.x - ngemm;
    if (local < 256)      wt_unit(local, tid, rpW1, rpW1t, 512, 4);
    else if (local < 320) wt_unit(local - 256, tid, rpW2, rpW2t, 128, 4);
    else if (local < 576) wt_unit(local - 320, tid, rgW1, rgW1t, 512, 4);
    else                  wt_unit(local - 576, tid, rgW2, rgW2t, 128, 4);
    return;
  }
  constexpr int KS = K >> 5;
  constexpr int NSTEP = K >> 6;
  constexpr int ABYTES = BM * 128;
  constexpr int BBYTES = 8192;
  constexpr int NA = BM >> 5;
  constexpr int WM_FR = BM >> 5;
  constexpr int V = NA + 2;
  __shared__ char lds[3 * (ABYTES + BBYTES)];
  char* AsB = lds;
  char* BsB = lds + 3 * ABYTES;

  const int bid = blockIdx.x;
  const int bx = bid % gx, by = (bid / gx) % gy, z = bid / (gx * gy);
  const int lane = tid & 63, w = tid >> 6;
  const int wm = w >> 1, wn = w & 1;
  const char* Ab = (const char*)(z ? A1 : A0);
  const char* Wb = (const char*)(z ? W1 : W0);
  const float* bias = z ? b1 : b0;
  char* Cb = (char*)(z ? C1 : C0);
  const int bm = bx * BM, bn = by * 64;
  const int lane16 = lane * 16;

  auto stage = [&](int buf, int st) {
#pragma unroll
    for (int u = 0; u < NA; ++u) {
      const int sl = w * NA + u;
      const char* src = Ab + ((size_t)((bm >> 4) + (sl >> 1)) * KS + st * 2 + (sl & 1)) * 1024 + lane16;
      __builtin_amdgcn_global_load_lds((gas_t)src, (las_t)(AsB + buf * ABYTES + sl * 1024), 16, 0, 0);
    }
#pragma unroll
    for (int u = 0; u < 2; ++u) {
      const int sl = w * 2 + u;
      const char* src = Wb + ((size_t)((bn >> 4) + (sl >> 1)) * KS + st * 2 + (sl & 1)) * 1024 + lane16;
      __builtin_amdgcn_global_load_lds((gas_t)src, (las_t)(BsB + buf * BBYTES + sl * 1024), 16, 0, 0);
    }
  };

  f32x4 acc[WM_FR][2] = {};
  stage(0, 0);
  stage(1, 1);
#pragma unroll
  for (int st = 0; st < NSTEP; ++st) {
    const int buf = st % 3;
    if (st + 2 < NSTEP) {
      stage((st + 2) % 3, st + 2);
      if constexpr (V == 6) asm volatile("s_waitcnt vmcnt(12)" ::: "memory");
      else                  asm volatile("s_waitcnt vmcnt(8)" ::: "memory");
    } else if (st + 1 < NSTEP) {
      if constexpr (V == 6) asm volatile("s_waitcnt vmcnt(6)" ::: "memory");
      else                  asm volatile("s_waitcnt vmcnt(4)" ::: "memory");
    } else {
      asm volatile("s_waitcnt vmcnt(0)" ::: "memory");
    }
    __builtin_amdgcn_s_barrier();
#pragma unroll
    for (int kss = 0; kss < 2; ++kss) {
      bf16x8 af[WM_FR], bfv[2];
#pragma unroll
      for (int i = 0; i < WM_FR; ++i)
        af[i] = *(const bf16x8*)(AsB + buf * ABYTES + ((wm * WM_FR + i) * 2 + kss) * 1024 + lane16);
#pragma unroll
      for (int j = 0; j < 2; ++j)
        bfv[j] = *(const bf16x8*)(BsB + buf * BBYTES + ((wn * 2 + j) * 2 + kss) * 1024 + lane16);
#pragma unroll
      for (int i = 0; i < WM_FR; ++i)
#pragma unroll
        for (int j = 0; j < 2; ++j)
          acc[i][j] = __builtin_amdgcn_mfma_f32_16x16x32_bf16(bfv[j], af[i], acc[i][j], 0, 0, 0);
    }
    __builtin_amdgcn_s_barrier();
  }

  const int l15 = lane & 15, hi = lane >> 4;
  const int NS = N >> 5;
  const int row0 = bm + wm * (BM / 2);
  const int col0 = bn + wn * 32;
  float sq[WM_FR];
  int ar[WM_FR];
#pragma unroll
  for (int i = 0; i < WM_FR; ++i) { sq[i] = 0.f; ar[i] = 0; }
  if (GB && z == 1) {
#pragma unroll
    for (int i = 0; i < WM_FR; ++i) ar[i] = aidx[row0 + i * 16 + l15];
  }
  float4 bi0 = *(const float4*)&bias[col0 + hi * 4];
  float4 bi1 = *(const float4*)&bias[col0 + 16 + hi * 4];
#pragma unroll
  for (int i = 0; i < WM_FR; ++i) {
    const int rfC = (row0 >> 4) + i;
    float v[8] = { acc[i][0][0] + bi0.x, acc[i][0][1] + bi0.y,
                   acc[i][0][2] + bi0.z, acc[i][0][3] + bi0.w,
                   acc[i][1][0] + bi1.x, acc[i][1][1] + bi1.y,
                   acc[i][1][2] + bi1.z, acc[i][1][3] + bi1.w };
    if (GB && z == 1) {
      float4 g0 = *(const float4*)&gW0f[(size_t)(256 + ar[i]) * N + col0 + hi * 4];
      float4 g1 = *(const float4*)&gW0f[(size_t)(256 + ar[i]) * N + col0 + 16 + hi * 4];
      v[0] += g0.x; v[1] += g0.y; v[2] += g0.z; v[3] += g0.w;
      v[4] += g1.x; v[5] += g1.y; v[6] += g1.z; v[7] += g1.w;
    }
    bf16x8 r;
#pragma unroll
    for (int t = 0; t < 8; ++t) {
      float vv = RELU ? fmaxf(v[t], 0.f) : v[t];
      unsigned short cv = f2bf(vv);
      r[t] = (short)cv;
      if (SQ) { float vb = bf2f(cv); sq[i] += vb * vb; }
    }
    *(bf16x8*)(Cb + (size_t)(rfC * NS + (col0 >> 5)) * 1024 + lane16) = r;
  }
  if (SQ && z == 1) {
#pragma unroll
    for (int i = 0; i < WM_FR; ++i) {
      float t = sq[i];
      t += __shfl_xor(t, 16, 64);
      t += __shfl_xor(t, 32, 64);
      if (lane < 16) atomicAdd(&sqp[row0 + i * 16 + lane], t);
    }
  }
}

// ---------------------------------------------------------------- logits: grid (32,16), 256 j/block,
// online softmax over 4 jf-groups (low VGPR), direct global B reads, single sqp.
__global__ __launch_bounds__(256) void logits_fm(
    const unsigned short* __restrict__ Zb, const unsigned short* __restrict__ Zpb,
    const float* __restrict__ sqp, float* __restrict__ wm_,
    float* __restrict__ wsum, float* __restrict__ wdiag) {
  const int tid = threadIdx.x, lane = tid & 63, w = tid >> 6;
  const int l15 = lane & 15, hi = lane >> 4;
  const int i0 = blockIdx.x * 128, jr = blockIdx.y;
  const int row32 = i0 + w * 32;
  const int jbase = jr * 256;
  const int lane16 = lane * 16;
  const char* Zc = (const char*)Zb;
  const char* Pc = (const char*)Zpb;

  bf16x8 afr[2][4];
#pragma unroll
  for (int rf = 0; rf < 2; ++rf)
#pragma unroll
    for (int ks = 0; ks < 4; ++ks)
      afr[rf][ks] = *(const bf16x8*)(Zc + (size_t)(((row32 >> 4) + rf) * 4 + ks) * 1024 + lane16);

  float m[2] = {-INFINITY, -INFINITY}, sv[2] = {0.f, 0.f}, dd[2] = {0.f, 0.f};
  bool hasd[2] = {false, false};
  const int grow0 = row32 + l15, grow1 = row32 + 16 + l15;

#pragma unroll
  for (int g = 0; g < 4; ++g) {
    f32x4 acc[2][4] = {};
#pragma unroll
    for (int ks = 0; ks < 4; ++ks)
#pragma unroll
      for (int q = 0; q < 4; ++q) {
        bf16x8 bfv = *(const bf16x8*)(Pc + (size_t)(((jbase >> 4) + g * 4 + q) * 4 + ks) * 1024 + lane16);
        acc[0][q] = __builtin_amdgcn_mfma_f32_16x16x32_bf16(bfv, afr[0][ks], acc[0][q], 0, 0, 0);
        acc[1][q] = __builtin_amdgcn_mfma_f32_16x16x32_bf16(bfv, afr[1][ks], acc[1][q], 0, 0, 0);
      }
    f32x4 spq[4];
#pragma unroll
    for (int q = 0; q < 4; ++q)
      spq[q] = *(const f32x4*)&sqp[jbase + (g * 4 + q) * 16 + hi * 4];
#pragma unroll
    for (int rf = 0; rf < 2; ++rf) {
      const int grow = rf ? grow1 : grow0;
      float lv[16];
      float lmax = -INFINITY;
#pragma unroll
      for (int q = 0; q < 4; ++q)
#pragma unroll
        for (int e = 0; e < 4; ++e) {
          const int j = jbase + (g * 4 + q) * 16 + hi * 4 + e;
          float x = (2.f * acc[rf][q][e] - spq[q][e]) * INV_T;
          lv[q * 4 + e] = x;
          lmax = fmaxf(lmax, x);
          if (j == grow) { dd[rf] = x; hasd[rf] = true; }
        }
      float mn = fmaxf(m[rf], lmax);
      float sc = __expf(m[rf] - mn);
      float ls = 0.f;
#pragma unroll
      for (int t = 0; t < 16; ++t) ls += __expf(lv[t] - mn);
      sv[rf] = sv[rf] * sc + ls;
      m[rf] = mn;
    }
  }

#pragma unroll
  for (int rf = 0; rf < 2; ++rf) {
    const int grow = rf ? grow1 : grow0;
    float mm = m[rf], ss = sv[rf];
#pragma unroll
    for (int off = 16; off <= 32; off <<= 1) {
      float mo = __shfl_xor(mm, off, 64);
      float so = __shfl_xor(ss, off, 64);
      float mn = fmaxf(mm, mo);
      ss = ss * __expf(mm - mn) + so * __expf(mo - mn);
      mm = mn;
    }
    if (hi == 0) {
      wm_[(size_t)jr * NR + grow] = mm;
      wsum[(size_t)jr * NR + grow] = ss;
    }
    if (hasd[rf]) wdiag[grow] = dd[rf];
  }
}

// ---------------------------------------------------------------- finalize (16 partials)
__global__ __launch_bounds__(256) void finalize(const float* __restrict__ wm,
    const float* __restrict__ wsum, const float* __restrict__ wdiag,
    float* __restrict__ out) {
  int r = blockIdx.x * 256 + threadIdx.x;
  float mm = wm[r];
  float ss = wsum[r];
#pragma unroll
  for (int p = 1; p < NJR; ++p) {
    float mo = wm[(size_t)p * NR + r];
    float so = wsum[(size_t)p * NR + r];
    float mn = fmaxf(mm, mo);
    ss = ss * __expf(mm - mn) + so * __expf(mo - mn);
    mm = mn;
  }
  float loss_r = mm + logf(ss) - wdiag[r];
  float v = loss_r;
#pragma unroll
  for (int off = 32; off; off >>= 1) v += __shfl_xor(v, off, 64);
  __shared__ float partial[4];
  if ((threadIdx.x & 63) == 0) partial[threadIdx.x >> 6] = v;
  __syncthreads();
  if (threadIdx.x == 0)
    atomicAdd(out, (partial[0] + partial[1] + partial[2] + partial[3]) * (1.0f / (float)NR));
}

// ---------------------------------------------------------------- launch (6 dispatches, low block counts)
extern "C" void kernel_launch(void* const* d_in, const int* in_sizes, int n_in,
                              void* d_out, int out_size, void* d_ws, size_t ws_size,
                              hipStream_t stream) {
  const float* s   = (const float*)d_in[0];
  const float* sp  = (const float*)d_in[1];
  const float* a1h = (const float*)d_in[2];
  const float* pW0 = (const float*)d_in[3];
  const float* pb0 = (const float*)d_in[4];
  const float* pW1 = (const float*)d_in[5];
  const float* pb1 = (const float*)d_in[6];
  const float* pW2 = (const float*)d_in[7];
  const float* pb2 = (const float*)d_in[8];
  const float* gW0 = (const float*)d_in[9];
  const float* gb0 = (const float*)d_in[10];
  const float* gW1 = (const float*)d_in[11];
  const float* gb1 = (const float*)d_in[12];
  const float* gW2 = (const float*)d_in[13];
  const float* gb2 = (const float*)d_in[14];

  char* p = (char*)d_ws;
  unsigned short* Sb   = (unsigned short*)p; p += (size_t)NR * 256 * 2;
  unsigned short* SPb  = (unsigned short*)p; p += (size_t)NR * 256 * 2;
  unsigned short* H1   = (unsigned short*)p; p += (size_t)2 * NR * HD * 2;
  unsigned short* H2   = (unsigned short*)p; p += (size_t)2 * NR * HD * 2;
  unsigned short* Zall = (unsigned short*)p; p += (size_t)2 * NR * 128 * 2;
  unsigned short* pW0t = (unsigned short*)p; p += (size_t)256 * 512 * 2;
  unsigned short* pW1t = (unsigned short*)p; p += (size_t)512 * 512 * 2;
  unsigned short* pW2t = (unsigned short*)p; p += (size_t)512 * 128 * 2;
  unsigned short* gW0t = (unsigned short*)p; p += (size_t)256 * 512 * 2;
  unsigned short* gW1t = (unsigned short*)p; p += (size_t)512 * 512 * 2;
  unsigned short* gW2t = (unsigned short*)p; p += (size_t)512 * 128 * 2;
  float* sqp  = (float*)p; p += (size_t)NR * 4;
  float* wm   = (float*)p; p += (size_t)NJR * NR * 4;
  float* wsm  = (float*)p; p += (size_t)NJR * NR * 4;
  float* wdg  = (float*)p; p += (size_t)NR * 4;
  int*   aidx = (int*)p;  p += (size_t)NR * 4;

  unsigned short* H1g = H1 + (size_t)NR * HD;
  unsigned short* H2g = H2 + (size_t)NR * HD;
  unsigned short* Zb  = Zall;
  unsigned short* Zpb = Zall + (size_t)NR * 128;

  dim3 blk(256);
  prep<<<580, blk, 0, stream>>>(s, sp, a1h, Sb, SPb, aidx, sqp,
                                pW0, pW0t, gW0, gW0t, (float*)d_out);

  // L0 (512 gemm blocks) + 640 rider W1/W2 transpose blocks
  gemm_p3<128, 256, true, true, false, true><<<1152, blk, 0, stream>>>(
      Sb, SPb, pW0t, gW0t, pb0, gb0, H1, H1g, nullptr, 512, 32, 8, aidx, gW0,
      pW1, pW1t, pW2, pW2t, gW1, gW1t, gW2, gW2t);

  gemm_p3<128, 512, true, false, false, false><<<512, blk, 0, stream>>>(
      H1, H1g, pW1t, gW1t, pb1, gb1, H2, H2g, nullptr, 512, 32, 8, nullptr, nullptr,
      nullptr, nullptr, nullptr, nullptr, nullptr, nullptr, nullptr, nullptr);

  gemm_p3<64, 512, false, false, true, false><<<256, blk, 0, stream>>>(
      H2, H2g, pW2t, gW2t, pb2, gb2, Zb, Zpb, sqp, 128, 64, 2, nullptr, nullptr,
      nullptr, nullptr, nullptr, nullptr, nullptr, nullptr, nullptr, nullptr);

  logits_fm<<<dim3(32, NJR), blk, 0, stream>>>(Zb, Zpb, sqp, wm, wsm, wdg);
  finalize<<<NR / 256, blk, 0, stream>>>(wm, wsm, wdg, (float*)d_out);
}